// Round 5
// baseline (352.945 us; speedup 1.0000x reference)
//
#include <hip/hip_runtime.h>

typedef _Float16 f16;
typedef _Float16 f16x4 __attribute__((ext_vector_type(4)));
typedef _Float16 f16x8 __attribute__((ext_vector_type(8)));
typedef float    f32x16 __attribute__((ext_vector_type(16)));

#define NB 32
#define TTOT 512
#define SSN 8256
#define PT 2064
#define EE 256
#define KCB 512

// ---------------- ws layout (bytes) ----------------
#define YB   ((size_t)NB*EE*PT*2)
#define LWB  ((size_t)EE*4096*2)
#define CBB  ((size_t)KCB*EE*2)
#define EBB  ((size_t)16384*EE*2)
#define OFF_Y0  ((size_t)0)
#define OFF_Y1  (YB)
#define OFF_LW0 (2*YB)
#define OFF_LW1 (2*YB + LWB)
#define OFF_CB0 (2*YB + 2*LWB)
#define OFF_CB1 (2*YB + 2*LWB + CBB)
#define OFF_HN  (2*YB + 2*LWB + 2*CBB)
#define OFF_E0  (OFF_HN + 4096)
#define OFF_E1  (OFF_E0 + EBB)
#define WS_NEED (OFF_E1 + EBB)

#define INV2048 4.8828125e-4f

struct h2 { f16 hi, lo; };
__device__ __forceinline__ h2 split2(float v) {
  h2 r;
  r.hi = (f16)v;
  r.lo = (f16)((v - (float)r.hi) * 2048.0f);
  return r;
}

__device__ __forceinline__ f16x8 ldsfrag(const f16* p) {
  union { f16x8 v8; f16x4 v4[2]; } u;
  u.v4[0] = *(const f16x4*)p;
  u.v4[1] = *(const f16x4*)(p + 4);
  return u.v8;
}

#define MFMA16(a,b,c) __builtin_amdgcn_mfma_f32_32x32x16_f16(a, b, c, 0, 0, 0)

// ================= k0: split lin_w + codebook, codebook half-norms =================
__global__ __launch_bounds__(256, 2)
void k0_split(const float* __restrict__ lin_w, const float* __restrict__ cbk,
              f16* __restrict__ lw0, f16* __restrict__ lw1,
              f16* __restrict__ cb0, f16* __restrict__ cb1, float* __restrict__ hn)
{
  const int tid = threadIdx.x, bid = blockIdx.x;
  if (bid < 256) {
    const float* src = lin_w + (size_t)bid * 4096;
    f16* d0 = lw0 + (size_t)bid * 4096;
    f16* d1 = lw1 + (size_t)bid * 4096;
#pragma unroll
    for (int i = 0; i < 4; ++i) {
      const int o = (tid + i * 256) * 4;
      const float4 v = *(const float4*)(src + o);
      f16x4 h0, h1;
      { h2 s = split2(v.x); h0[0] = s.hi; h1[0] = s.lo; }
      { h2 s = split2(v.y); h0[1] = s.hi; h1[1] = s.lo; }
      { h2 s = split2(v.z); h0[2] = s.hi; h1[2] = s.lo; }
      { h2 s = split2(v.w); h0[3] = s.hi; h1[3] = s.lo; }
      *(f16x4*)(d0 + o) = h0; *(f16x4*)(d1 + o) = h1;
    }
  } else {
    const int r = (bid - 256) * 64 + (tid >> 2), q = tid & 3;
    const float* src = cbk + (size_t)r * 256 + q * 64;
    f16* d0 = cb0 + (size_t)r * 256 + q * 64;
    f16* d1 = cb1 + (size_t)r * 256 + q * 64;
    float s = 0.f;
#pragma unroll
    for (int i = 0; i < 16; ++i) {
      const float4 v = *(const float4*)(src + i * 4);
      s = fmaf(v.x, v.x, s); s = fmaf(v.y, v.y, s);
      s = fmaf(v.z, v.z, s); s = fmaf(v.w, v.w, s);
      f16x4 h0, h1;
      { h2 t = split2(v.x); h0[0] = t.hi; h1[0] = t.lo; }
      { h2 t = split2(v.y); h0[1] = t.hi; h1[1] = t.lo; }
      { h2 t = split2(v.z); h0[2] = t.hi; h1[2] = t.lo; }
      { h2 t = split2(v.w); h0[3] = t.hi; h1[3] = t.lo; }
      *(f16x4*)(d0 + i * 4) = h0; *(f16x4*)(d1 + i * 4) = h1;
    }
    s += __shfl_xor(s, 1, 64);
    s += __shfl_xor(s, 2, 64);
    if (q == 0) hn[r] = 0.5f * s;
  }
}

// ================= k1: conv -> y limbs. x held in registers; no LDS. =================
__global__ __launch_bounds__(256, 2)
void k1_conv(const float* __restrict__ x, const float* __restrict__ cw,
             const float* __restrict__ cb, f16* __restrict__ y0, f16* __restrict__ y1)
{
  const int bid = blockIdx.x;                 // 32*18 = 576
  const int b = bid / 18, rem = bid % 18;
  const int eq = rem / 9, ptile = rem % 9;
  const int p = ptile * 256 + threadIdx.x;
  const bool valid = p < PT;
  const int pc = valid ? p : (PT - 1);
  float4 xv[8];
#pragma unroll
  for (int v = 0; v < 8; ++v)
    xv[v] = *(const float4*)(x + ((size_t)b * 8 + v) * SSN + 4 * pc);
  const int e0 = eq * 128;
  float4 wc[8], wn[8];
#pragma unroll
  for (int v = 0; v < 8; ++v) wc[v] = *(const float4*)(cw + (size_t)e0 * 32 + v * 4);
  for (int ep = e0; ep < e0 + 128; ++ep) {
    const int epn = (ep + 1 < e0 + 128) ? ep + 1 : ep;
#pragma unroll
    for (int v = 0; v < 8; ++v) wn[v] = *(const float4*)(cw + (size_t)epn * 32 + v * 4);
    float a = cb[ep];
#pragma unroll
    for (int v = 0; v < 8; ++v) {
      a = fmaf(xv[v].x, wc[v].x, a);
      a = fmaf(xv[v].y, wc[v].y, a);
      a = fmaf(xv[v].z, wc[v].z, a);
      a = fmaf(xv[v].w, wc[v].w, a);
    }
    a = fmaxf(a, 0.f);
    if (valid) {
      const h2 s = split2(a);
      const size_t o = ((size_t)b * EE + ep) * PT + p;
      y0[o] = s.hi; y1[o] = s.lo;
    }
#pragma unroll
    for (int v = 0; v < 8; ++v) wc[v] = wn[v];
  }
}

// ================= k2: linear GEMM via MFMA -> e limbs =================
// C[w][eo] = sum_k y[w,k] * lin_w[eo,k];  512 blocks = 256 M-tiles(64w) x 2 N-halves(128eo)
// B-fragments prefetched 4 ke-steps ahead (slot-static circular buffer, slot = ke).
__global__ __launch_bounds__(256, 2)
void k2_linear(const f16* __restrict__ yh0, const f16* __restrict__ yh1,
               const f16* __restrict__ lw0, const f16* __restrict__ lw1,
               const float* __restrict__ lin_b,
               f16* __restrict__ eh0, f16* __restrict__ eh1)
{
  __shared__ __align__(16) f16 ysh[2][2][4][272];   // [buf][limb][e'mod4][pos]
  const int tid = threadIdx.x;
  // XCD-aware swizzle over 512 blocks (bijective: 512 % 8 == 0)
  const int sw = (blockIdx.x & 7) * 64 + (blockIdx.x >> 3);
  const int nh = sw >> 8, mt = sw & 255;
  const int b = mt >> 3;
  const int p0 = (mt & 7) * 256;
  const int lane = tid & 63, wv = tid >> 6;
  const int m = wv >> 1, nq = wv & 1;
  const int hi = lane >> 5, lo = lane & 31;

  const f16* pB[2][2];
#pragma unroll
  for (int n = 0; n < 2; ++n) {
    const int eo = nh * 128 + (nq * 2 + n) * 32 + lo;
    pB[n][0] = lw0 + (size_t)eo * 4096 + 8 * hi;
    pB[n][1] = lw1 + (size_t)eo * 4096 + 8 * hi;
  }
  const int aoff = 4 * (m * 32 + lo) + 8 * hi;

  const int sr = tid >> 5, sc = tid & 31;          // stage row 0..7, chunk 0..31
  const int slimb = sr >> 2, ske = sr & 3;
  const bool has2 = sc < 2;
  const f16* ysrc = (slimb ? yh1 : yh0);

  f32x16 accH[2], accL[2];
#pragma unroll
  for (int n = 0; n < 2; ++n)
#pragma unroll
    for (int r = 0; r < 16; ++r) { accH[n][r] = 0.f; accL[n][r] = 0.f; }

  // ---- B prefetch prologue: slots 0..3 <- ep 0..3 ----
  f16x8 bf[4][2][2];   // [slot(=ke)][n][limb]
#pragma unroll
  for (int d = 0; d < 4; ++d)
#pragma unroll
    for (int n = 0; n < 2; ++n) {
      bf[d][n][0] = *(const f16x8*)(pB[n][0] + (size_t)d * 16);
      bf[d][n][1] = *(const f16x8*)(pB[n][1] + (size_t)d * 16);
    }

  { // prologue: stage ss=0 into buf0
    const f16* src = ysrc + ((size_t)(b * EE + ske) * PT + p0) + sc * 8;
    const float4 sA = *(const float4*)src;
    float4 sB{};
    if (has2) sB = *(const float4*)(src + 256);
    f16* dst = &ysh[0][slimb][ske][sc * 8];
    *(float4*)dst = sA;
    if (has2) *(float4*)(dst + 256) = sB;
  }
  __syncthreads();

  for (int ss = 0; ss < 64; ++ss) {
    const int cur = ss & 1;
    const int ssn = (ss < 63) ? ss + 1 : 63;
    // issue next-tile staging loads early (landed after the ke loop)
    const f16* src = ysrc + ((size_t)(b * EE + ssn * 4 + ske) * PT + p0) + sc * 8;
    const float4 sA = *(const float4*)src;
    float4 sB{};
    if (has2) sB = *(const float4*)(src + 256);

    // A-fragments for ke=0
    const f16* ab0 = &ysh[cur][0][0][0] + aoff;
    f16x8 a0 = ldsfrag(ab0);
    f16x8 a1 = ldsfrag(ab0 + 4 * 272);

#pragma unroll
    for (int ke = 0; ke < 4; ++ke) {
      // prefetch next ke's A-fragments from LDS
      f16x8 a0n, a1n;
      if (ke < 3) {
        const f16* abn = &ysh[cur][0][ke + 1][0] + aoff;
        a0n = ldsfrag(abn);
        a1n = ldsfrag(abn + 4 * 272);
      }
      // consume slot ke
#pragma unroll
      for (int n = 0; n < 2; ++n) {
        accH[n] = MFMA16(a0, bf[ke][n][0], accH[n]);
        accL[n] = MFMA16(a0, bf[ke][n][1], accL[n]);
        accL[n] = MFMA16(a1, bf[ke][n][0], accL[n]);
      }
      // reload slot ke from ep+4 (4-deep in-flight window)
      {
        const int epn = ss * 4 + ke + 4;
        const size_t off = (size_t)((epn < 256) ? epn : 255) * 16;
#pragma unroll
        for (int n = 0; n < 2; ++n) {
          bf[ke][n][0] = *(const f16x8*)(pB[n][0] + off);
          bf[ke][n][1] = *(const f16x8*)(pB[n][1] + off);
        }
      }
      if (ke < 3) { a0 = a0n; a1 = a1n; }
    }

    { // write staged rows into the other buffer
      f16* dst = &ysh[cur ^ 1][slimb][ske][sc * 8];
      *(float4*)dst = sA;
      if (has2) *(float4*)(dst + 256) = sB;
    }
    __syncthreads();
  }

  // epilogue: e = accH + accL/2048 + lin_b; split to limbs; store
#pragma unroll
  for (int n = 0; n < 2; ++n) {
    const int eo = nh * 128 + (nq * 2 + n) * 32 + lo;
    const float lb = lin_b[eo];
#pragma unroll
    for (int r = 0; r < 16; ++r) {
      const int wloc = m * 32 + (r & 3) + 8 * (r >> 2) + 4 * hi;
      const float v = accH[n][r] + accL[n][r] * INV2048 + lb;
      const h2 s = split2(v);
      const size_t o = (size_t)(mt * 64 + wloc) * EE + eo;
      eh0[o] = s.hi; eh1[o] = s.lo;
    }
  }
}

// ================= k3: distance MFMA + argmax(-argmin) + gather =================
__global__ __launch_bounds__(512, 1)
void k3_dist(const f16* __restrict__ eh0, const f16* __restrict__ eh1,
             const f16* __restrict__ cb0, const f16* __restrict__ cb1,
             const float* __restrict__ hn, const float* __restrict__ cbk,
             float* __restrict__ out)
{
  __shared__ __align__(16) f16 esh[2][64][136];   // [limb][w][k-half]
  __shared__ float scs[4][64];
  __shared__ int   scj[4][64];
  __shared__ int   bestj[64];
  const int tid = threadIdx.x;
  const int w0 = blockIdx.x * 64;
  const int lane = tid & 63, wv = tid >> 6;
  const int m = wv & 1, jg = wv >> 1;
  const int hi = lane >> 5, lo = lane & 31;

  const f16* pB[4][2];
  float hnv[4];
#pragma unroll
  for (int q = 0; q < 4; ++q) {
    const int j = (jg * 4 + q) * 32 + lo;
    pB[q][0] = cb0 + (size_t)j * EE + 8 * hi;
    pB[q][1] = cb1 + (size_t)j * EE + 8 * hi;
    hnv[q] = hn[j];
  }
  f32x16 accH[4], accL[4];
#pragma unroll
  for (int q = 0; q < 4; ++q)
#pragma unroll
    for (int r = 0; r < 16; ++r) { accH[q][r] = 0.f; accL[q][r] = 0.f; }

  const int ar = m * 32 + lo;
  f16x8 BA[4][2], BB[4][2];
#pragma unroll
  for (int q = 0; q < 4; ++q) {
    BA[q][0] = *(const f16x8*)(pB[q][0]);
    BA[q][1] = *(const f16x8*)(pB[q][1]);
  }

  for (int kh = 0; kh < 2; ++kh) {
    if (kh) __syncthreads();   // prior half's reads done before overwrite
    { // stage e-limb half: rows 64, 128 k each
      const int r = tid >> 3, c8 = tid & 7;
      const f16* s0 = eh0 + (size_t)(w0 + r) * EE + kh * 128;
      const f16* s1 = eh1 + (size_t)(w0 + r) * EE + kh * 128;
#pragma unroll
      for (int i = 0; i < 2; ++i) {
        const int c = (c8 * 2 + i) * 8;
        *(float4*)&esh[0][r][c] = *(const float4*)(s0 + c);
        *(float4*)&esh[1][r][c] = *(const float4*)(s1 + c);
      }
    }
    __syncthreads();
#pragma unroll
    for (int ksl = 0; ksl < 8; ++ksl) {
      const int ks = kh * 8 + ksl;
      const int ksn = (ks < 15) ? ks + 1 : 15;
      const f16x8 a0 = *(const f16x8*)(&esh[0][ar][0] + ksl * 16 + 8 * hi);
      const f16x8 a1 = *(const f16x8*)(&esh[1][ar][0] + ksl * 16 + 8 * hi);
      if ((ks & 1) == 0) {
#pragma unroll
        for (int q = 0; q < 4; ++q) {
          BB[q][0] = *(const f16x8*)(pB[q][0] + (size_t)ksn * 16);
          BB[q][1] = *(const f16x8*)(pB[q][1] + (size_t)ksn * 16);
        }
#pragma unroll
        for (int q = 0; q < 4; ++q) {
          accH[q] = MFMA16(a0, BA[q][0], accH[q]);
          accL[q] = MFMA16(a0, BA[q][1], accL[q]);
          accL[q] = MFMA16(a1, BA[q][0], accL[q]);
        }
      } else {
#pragma unroll
        for (int q = 0; q < 4; ++q) {
          BA[q][0] = *(const f16x8*)(pB[q][0] + (size_t)ksn * 16);
          BA[q][1] = *(const f16x8*)(pB[q][1] + (size_t)ksn * 16);
        }
#pragma unroll
        for (int q = 0; q < 4; ++q) {
          accH[q] = MFMA16(a0, BB[q][0], accH[q]);
          accL[q] = MFMA16(a0, BB[q][1], accL[q]);
          accL[q] = MFMA16(a1, BB[q][0], accL[q]);
        }
      }
    }
  }

  // per-w argmax over j (min-index tie-break)
#pragma unroll
  for (int r = 0; r < 16; ++r) {
    float bs = accH[0][r] + accL[0][r] * INV2048 - hnv[0];
    int   bj = (jg * 4 + 0) * 32 + lo;
#pragma unroll
    for (int q = 1; q < 4; ++q) {
      const float s = accH[q][r] + accL[q][r] * INV2048 - hnv[q];
      const int   j = (jg * 4 + q) * 32 + lo;
      if (s > bs) { bs = s; bj = j; }   // ascending j: strict > keeps lowest
    }
#pragma unroll
    for (int d = 1; d < 32; d <<= 1) {
      const float os = __shfl_xor(bs, d, 64);
      const int   oj = __shfl_xor(bj, d, 64);
      if (os > bs || (os == bs && oj < bj)) { bs = os; bj = oj; }
    }
    if (lo == 0) {
      const int wloc = m * 32 + (r & 3) + 8 * (r >> 2) + 4 * hi;
      scs[jg][wloc] = bs; scj[jg][wloc] = bj;
    }
  }
  __syncthreads();
  if (tid < 64) {
    float bs = scs[0][tid]; int bj = scj[0][tid];
#pragma unroll
    for (int g = 1; g < 4; ++g) {
      const float s = scs[g][tid]; const int j = scj[g][tid];
      if (s > bs || (s == bs && j < bj)) { bs = s; bj = j; }
    }
    bestj[tid] = bj;
  }
  __syncthreads();
  { // gather codebook rows to output
    const int rr = tid >> 6;          // 0..7
    const int c4 = (tid & 63) * 4;
#pragma unroll
    for (int pass = 0; pass < 8; ++pass) {
      const int r = pass * 8 + rr;
      const int jb = bestj[r];
      const float4 v = *(const float4*)(cbk + (size_t)jb * EE + c4);
      *(float4*)(out + (size_t)(w0 + r) * EE + c4) = v;
    }
  }
}

// ================= fallback: R1 fused VALU kernel (known-good) =================
#define V 8
#define LAGS 4
#define WIN 64
#define STEP 16
#define CONV_OUT 16
#define WPB 16
#define TPB 256
#define NWORD 19
#define YSTRIDE 80
#define XSPAN 304
#define FOFF_YS   0
#define FOFF_XS   10240
#define FOFF_ES   10240
#define FOFF_SC   0
#define FOFF_SI   4096
#define FOFF_PS   8192
#define FOFF_PI   8448
#define FOFF_IW   8704
#define SMEM_FLOATS 14336

__device__ __forceinline__ float f4get(const float4& v, int i) {
  return i == 0 ? v.x : (i == 1 ? v.y : (i == 2 ? v.z : v.w));
}

__device__ __forceinline__ float conv_one(const float* xs, int p, const float4* cw, float cb0) {
  float a = cb0;
#pragma unroll
  for (int v = 0; v < V; ++v) {
    const float4 xv = *(const float4*)(xs + v * XSPAN + 4 * p);
    a = fmaf(xv.x, cw[v].x, a);
    a = fmaf(xv.y, cw[v].y, a);
    a = fmaf(xv.z, cw[v].z, a);
    a = fmaf(xv.w, cw[v].w, a);
  }
  return fmaxf(a, 0.0f);
}

__global__ __launch_bounds__(TPB, 2)
void tok_fused(const float* __restrict__ x, const float* __restrict__ conv_w,
               const float* __restrict__ conv_b, const float* __restrict__ lin_w,
               const float* __restrict__ lin_b, const float* __restrict__ cbk,
               float* __restrict__ out)
{
  __shared__ float smem[SMEM_FLOATS];
  float* ys = smem + FOFF_YS;
  float* xs = smem + FOFF_XS;
  float* es = smem + FOFF_ES;
  float* sc = smem + FOFF_SC;
  int*   si = (int*)(smem + FOFF_SI);
  float* ps = smem + FOFF_PS;
  int*   pi = (int*)(smem + FOFF_PI);
  int*   iw = (int*)(smem + FOFF_IW);
  const int tid = threadIdx.x;
  const int b   = blockIdx.x >> 5;
  const int t0  = (blockIdx.x & 31) * WPB;
  const float* xb = x + (size_t)b * V * SSN + (size_t)t0 * STEP;
#pragma unroll
  for (int v = 0; v < V; ++v)
    for (int j = tid; j < XSPAN; j += TPB)
      xs[v * XSPAN + j] = xb[(size_t)v * SSN + j];
  double accd[WPB];
#pragma unroll
  for (int w = 0; w < WPB; ++w) accd[w] = 0.0;
  for (int half = 0; half < 2; ++half) {
    __syncthreads();
    {
      const int ep  = half * 128 + (tid >> 1);
      const int row = ep & 127;
      float4 cw[V];
      const float4* cwp = (const float4*)(conv_w + (size_t)ep * (V * LAGS));
#pragma unroll
      for (int v = 0; v < V; ++v) cw[v] = cwp[v];
      const float cb0 = conv_b[ep];
      const int c0 = (tid & 1) ? 10 : 0;
      const int c1 = (tid & 1) ? NWORD : 10;
      for (int c = c0; c < c1; ++c) {
        const int p = 4 * c;
        float r0 = conv_one(xs, p + 0, cw, cb0);
        float r1 = conv_one(xs, p + 1, cw, cb0);
        float r2 = conv_one(xs, p + 2, cw, cb0);
        float r3 = conv_one(xs, p + 3, cw, cb0);
        *(float4*)(ys + row * YSTRIDE + 4 * c) = make_float4(r0, r1, r2, r3);
      }
    }
    __syncthreads();
    const float* lwbase = lin_w + (size_t)tid * (EE * CONV_OUT) + half * (128 * CONV_OUT);
    float4 nA, nB, nC, nD;
    {
      const float4* p4 = (const float4*)(lwbase);
      nA = p4[0]; nB = p4[1]; nC = p4[2]; nD = p4[3];
    }
    for (int er = 0; er < 128; ++er) {
      const float4 lA = nA, lB = nB, lC = nC, lD = nD;
      const int ern = (er + 1) & 127;
      {
        const float4* p4 = (const float4*)(lwbase + ern * CONV_OUT);
        nA = p4[0]; nB = p4[1]; nC = p4[2]; nD = p4[3];
      }
      float4 yr[NWORD];
      const float4* yp = (const float4*)(ys + er * YSTRIDE);
#pragma unroll
      for (int q = 0; q < NWORD; ++q) yr[q] = yp[q];
      float it[WPB];
#pragma unroll
      for (int w = 0; w < WPB; ++w) it[w] = 0.0f;
#pragma unroll
      for (int o = 0; o < CONV_OUT; ++o) {
        const float lw_o = f4get(o < 4 ? lA : (o < 8 ? lB : (o < 12 ? lC : lD)), o & 3);
#pragma unroll
        for (int w = 0; w < WPB; ++w) {
          const int p = 4 * w + o;
          it[w] = fmaf(lw_o, f4get(yr[p >> 2], p & 3), it[w]);
        }
      }
#pragma unroll
      for (int w = 0; w < WPB; ++w) accd[w] += (double)it[w];
    }
  }
#pragma unroll
  for (int w = 0; w < WPB; ++w)
    es[w * EE + tid] = (float)accd[w] + lin_b[tid];
  __syncthreads();
  float s_best[WPB];
  int   i_best[WPB];
#pragma unroll
  for (int jj = 0; jj < 2; ++jj) {
    const int j = tid + jj * 256;
    const float4* cbp = (const float4*)(cbk + (size_t)j * EE);
    double sdd[WPB];
    float  sd32[WPB];
#pragma unroll
    for (int w = 0; w < WPB; ++w) { sdd[w] = 0.0; sd32[w] = 0.f; }
    double ndd = 0.0;
    float  nd32 = 0.f;
    float4 c4n = cbp[0];
    for (int i16 = 0; i16 < 4; ++i16) {
      for (int i4i = 0; i4i < 16; ++i4i) {
        const int i4 = i16 * 16 + i4i;
        const float4 c4 = c4n;
        c4n = cbp[(i4 + 1 <= 63) ? (i4 + 1) : 63];
        nd32 = fmaf(c4.x, c4.x, nd32);
        nd32 = fmaf(c4.y, c4.y, nd32);
        nd32 = fmaf(c4.z, c4.z, nd32);
        nd32 = fmaf(c4.w, c4.w, nd32);
#pragma unroll
        for (int w = 0; w < WPB; ++w) {
          const float4 e4 = *(const float4*)(es + w * EE + i4 * 4);
          sd32[w] = fmaf(c4.x, e4.x, sd32[w]);
          sd32[w] = fmaf(c4.y, e4.y, sd32[w]);
          sd32[w] = fmaf(c4.z, e4.z, sd32[w]);
          sd32[w] = fmaf(c4.w, e4.w, sd32[w]);
        }
      }
#pragma unroll
      for (int w = 0; w < WPB; ++w) { sdd[w] += (double)sd32[w]; sd32[w] = 0.f; }
      ndd += (double)nd32; nd32 = 0.f;
    }
#pragma unroll
    for (int w = 0; w < WPB; ++w) {
      const float s = (float)(sdd[w] - 0.5 * ndd);
      if (jj == 0) { s_best[w] = s; i_best[w] = j; }
      else if (s > s_best[w]) { s_best[w] = s; i_best[w] = j; }
    }
  }
#pragma unroll
  for (int w = 0; w < WPB; ++w) {
    sc[w * EE + tid] = s_best[w];
    si[w * EE + tid] = i_best[w];
  }
  __syncthreads();
  {
    const int w = tid >> 4, seg = tid & 15;
    float mm = -INFINITY; int mi = 0x7fffffff;
    for (int t = seg * 16; t < seg * 16 + 16; ++t) {
      const float s = sc[w * EE + t];
      const int   jx = si[w * EE + t];
      if (s > mm || (s == mm && jx < mi)) { mm = s; mi = jx; }
    }
    ps[w * 16 + seg] = mm; pi[w * 16 + seg] = mi;
  }
  __syncthreads();
  if (tid < WPB) {
    const int w = tid;
    float mm = -INFINITY; int mi = 0x7fffffff;
    for (int t = 0; t < 16; ++t) {
      const float s = ps[w * 16 + t];
      const int   jx = pi[w * 16 + t];
      if (s > mm || (s == mm && jx < mi)) { mm = s; mi = jx; }
    }
    iw[w] = mi;
  }
  __syncthreads();
  const size_t outb = ((size_t)b * TTOT + t0) * EE;
#pragma unroll
  for (int w = 0; w < WPB; ++w)
    out[outb + (size_t)w * EE + tid] = cbk[(size_t)iw[w] * EE + tid];
}

// ================= launch =================
extern "C" void kernel_launch(void* const* d_in, const int* in_sizes, int n_in,
                              void* d_out, int out_size, void* d_ws, size_t ws_size,
                              hipStream_t stream) {
  const float* x      = (const float*)d_in[0];
  const float* conv_w = (const float*)d_in[1];
  const float* conv_b = (const float*)d_in[2];
  const float* lin_w  = (const float*)d_in[3];
  const float* lin_b  = (const float*)d_in[4];
  const float* cbk    = (const float*)d_in[5];
  float* out = (float*)d_out;

  if (ws_size < WS_NEED) {
    tok_fused<<<dim3(32 * 32), dim3(TPB), 0, stream>>>(x, conv_w, conv_b, lin_w, lin_b, cbk, out);
    return;
  }
  char* ws = (char*)d_ws;
  f16*   y0  = (f16*)(ws + OFF_Y0);
  f16*   y1  = (f16*)(ws + OFF_Y1);
  f16*   lw0 = (f16*)(ws + OFF_LW0);
  f16*   lw1 = (f16*)(ws + OFF_LW1);
  f16*   cb0 = (f16*)(ws + OFF_CB0);
  f16*   cb1 = (f16*)(ws + OFF_CB1);
  float* hn  = (float*)(ws + OFF_HN);
  f16*   e0  = (f16*)(ws + OFF_E0);
  f16*   e1  = (f16*)(ws + OFF_E1);

  k0_split<<<264, 256, 0, stream>>>(lin_w, cbk, lw0, lw1, cb0, cb1, hn);
  k1_conv <<<576, 256, 0, stream>>>(x, conv_w, conv_b, y0, y1);
  k2_linear<<<512, 256, 0, stream>>>(y0, y1, lw0, lw1, lin_b, e0, e1);
  k3_dist <<<256, 512, 0, stream>>>(e0, e1, cb0, cb1, hn, cbk, out);
}

// Round 6
// 195.628 us; speedup vs baseline: 1.8042x; 1.8042x over previous
//
#include <hip/hip_runtime.h>

typedef _Float16 f16;
typedef _Float16 f16x4 __attribute__((ext_vector_type(4)));
typedef _Float16 f16x8 __attribute__((ext_vector_type(8)));
typedef float    f32x16 __attribute__((ext_vector_type(16)));

#define NB 32
#define TTOT 512
#define SSN 8256
#define PT 2064
#define EE 256
#define KCB 512

// ---------------- ws layout (bytes) ----------------
#define YB   ((size_t)NB*EE*PT*2)
#define LWB  ((size_t)EE*4096*2)
#define CBB  ((size_t)KCB*EE*2)
#define EBB  ((size_t)16384*EE*2)
#define OFF_Y0  ((size_t)0)
#define OFF_Y1  (YB)
#define OFF_LW0 (2*YB)
#define OFF_LW1 (2*YB + LWB)
#define OFF_CB0 (2*YB + 2*LWB)
#define OFF_CB1 (2*YB + 2*LWB + CBB)
#define OFF_HN  (2*YB + 2*LWB + 2*CBB)
#define OFF_E0  (OFF_HN + 4096)
#define OFF_E1  (OFF_E0 + EBB)
#define WS_NEED (OFF_E1 + EBB)

#define INV2048 4.8828125e-4f

struct h2 { f16 hi, lo; };
__device__ __forceinline__ h2 split2(float v) {
  h2 r;
  r.hi = (f16)v;
  r.lo = (f16)((v - (float)r.hi) * 2048.0f);
  return r;
}

__device__ __forceinline__ f16x8 ldsfrag(const f16* p) {
  union { f16x8 v8; f16x4 v4[2]; } u;
  u.v4[0] = *(const f16x4*)p;
  u.v4[1] = *(const f16x4*)(p + 4);
  return u.v8;
}

#define MFMA16(a,b,c) __builtin_amdgcn_mfma_f32_32x32x16_f16(a, b, c, 0, 0, 0)

// ================= k0: repack lin_w + codebook into MFMA-fragment order =================
// lwp[limb]: frag(nb 0..7, ep 0..255, lane 0..63) of 8 f16, addr = ((nb*256+ep)*64+lane)*8
//   holds lin_w[eo = nb*32 + (lane&31)][k = ep*16 + 8*(lane>>5) + i] limb
// cbp[limb]: frag(jb 0..15, ks 0..15, lane) addr = ((jb*16+ks)*64+lane)*8
//   holds cbk[j = jb*32 + (lane&31)][k = ks*16 + 8*(lane>>5) + i] limb
__global__ __launch_bounds__(256, 2)
void k0_split(const float* __restrict__ lin_w, const float* __restrict__ cbk,
              f16* __restrict__ lwp0, f16* __restrict__ lwp1,
              f16* __restrict__ cbp0, f16* __restrict__ cbp1, float* __restrict__ hn)
{
  __shared__ float part[4][32];
  const int tid = threadIdx.x, bid = blockIdx.x;
  if (bid < 256) {
    const int eo = bid, nb = eo >> 5, lo = eo & 31;
    const int ep = tid;
    const float* src = lin_w + (size_t)eo * 4096 + ep * 16;
    float f[16];
    *(float4*)(f + 0)  = ((const float4*)src)[0];
    *(float4*)(f + 4)  = ((const float4*)src)[1];
    *(float4*)(f + 8)  = ((const float4*)src)[2];
    *(float4*)(f + 12) = ((const float4*)src)[3];
    union { f16x8 v; f16 e[8]; } a0, a1, b0, b1;
#pragma unroll
    for (int i = 0; i < 8; ++i) {
      { h2 s = split2(f[i]);     a0.e[i] = s.hi; a1.e[i] = s.lo; }
      { h2 s = split2(f[i + 8]); b0.e[i] = s.hi; b1.e[i] = s.lo; }
    }
    const size_t base = ((size_t)nb * 16384 + (size_t)ep * 64 + lo) * 8;
    *(f16x8*)(lwp0 + base)       = a0.v;   // hi half-k: lane hi=0
    *(f16x8*)(lwp0 + base + 256) = b0.v;   // lane hi=1 slot (+32 lanes * 8)
    *(f16x8*)(lwp1 + base)       = a1.v;
    *(f16x8*)(lwp1 + base + 256) = b1.v;
  } else {
    const int jb = bid - 256;              // 0..15
    const int lane = tid & 63, ksg = tid >> 6;
    const int hi = lane >> 5, lo = lane & 31;
    const int j = jb * 32 + lo;
    float s = 0.f;
#pragma unroll
    for (int kq = 0; kq < 4; ++kq) {
      const int ks = ksg * 4 + kq;
      const float* src = cbk + (size_t)j * 256 + ks * 16 + 8 * hi;
      float f[8];
      *(float4*)(f + 0) = ((const float4*)src)[0];
      *(float4*)(f + 4) = ((const float4*)src)[1];
      union { f16x8 v; f16 e[8]; } h0, h1;
#pragma unroll
      for (int i = 0; i < 8; ++i) {
        s = fmaf(f[i], f[i], s);
        h2 t = split2(f[i]); h0.e[i] = t.hi; h1.e[i] = t.lo;
      }
      const size_t base = ((size_t)jb * 1024 + (size_t)ks * 64 + lane) * 8;
      *(f16x8*)(cbp0 + base) = h0.v;
      *(f16x8*)(cbp1 + base) = h1.v;
    }
    s += __shfl_xor(s, 32, 64);            // fold hi=0/1
    if (lane < 32) part[ksg][lane] = s;
    __syncthreads();
    if (tid < 32)
      hn[jb * 32 + tid] = 0.5f * (part[0][tid] + part[1][tid] + part[2][tid] + part[3][tid]);
  }
}

// ================= k1: conv -> y limbs. x held in registers; no LDS. =================
__global__ __launch_bounds__(256, 2)
void k1_conv(const float* __restrict__ x, const float* __restrict__ cw,
             const float* __restrict__ cb, f16* __restrict__ y0, f16* __restrict__ y1)
{
  const int bid = blockIdx.x;                 // 32*18 = 576
  const int b = bid / 18, rem = bid % 18;
  const int eq = rem / 9, ptile = rem % 9;
  const int p = ptile * 256 + threadIdx.x;
  const bool valid = p < PT;
  const int pc = valid ? p : (PT - 1);
  float4 xv[8];
#pragma unroll
  for (int v = 0; v < 8; ++v)
    xv[v] = *(const float4*)(x + ((size_t)b * 8 + v) * SSN + 4 * pc);
  const int e0 = eq * 128;
  float4 wc[8], wn[8];
#pragma unroll
  for (int v = 0; v < 8; ++v) wc[v] = *(const float4*)(cw + (size_t)e0 * 32 + v * 4);
  for (int ep = e0; ep < e0 + 128; ++ep) {
    const int epn = (ep + 1 < e0 + 128) ? ep + 1 : ep;
#pragma unroll
    for (int v = 0; v < 8; ++v) wn[v] = *(const float4*)(cw + (size_t)epn * 32 + v * 4);
    float a = cb[ep];
#pragma unroll
    for (int v = 0; v < 8; ++v) {
      a = fmaf(xv[v].x, wc[v].x, a);
      a = fmaf(xv[v].y, wc[v].y, a);
      a = fmaf(xv[v].z, wc[v].z, a);
      a = fmaf(xv[v].w, wc[v].w, a);
    }
    a = fmaxf(a, 0.f);
    if (valid) {
      const h2 s = split2(a);
      const size_t o = ((size_t)b * EE + ep) * PT + p;
      y0[o] = s.hi; y1[o] = s.lo;
    }
#pragma unroll
    for (int v = 0; v < 8; ++v) wc[v] = wn[v];
  }
}

// ================= k2: linear GEMM via MFMA -> e limbs =================
// C[w][eo] = sum_k y[w,k] * lin_w[eo,k];  512 blocks = 256 M-tiles(64w) x 2 N-halves(128eo)
// B-fragments: packed layout, each load is wave-contiguous 1KB; 4-deep slot prefetch.
__global__ __launch_bounds__(256, 2)
void k2_linear(const f16* __restrict__ yh0, const f16* __restrict__ yh1,
               const f16* __restrict__ lwp0, const f16* __restrict__ lwp1,
               const float* __restrict__ lin_b,
               f16* __restrict__ eh0, f16* __restrict__ eh1)
{
  __shared__ __align__(16) f16 ysh[2][2][4][272];   // [buf][limb][e'mod4][pos]
  const int tid = threadIdx.x;
  // XCD-aware swizzle over 512 blocks (bijective: 512 % 8 == 0)
  const int sw = (blockIdx.x & 7) * 64 + (blockIdx.x >> 3);
  const int nh = sw >> 8, mt = sw & 255;
  const int b = mt >> 3;
  const int p0 = (mt & 7) * 256;
  const int lane = tid & 63, wv = tid >> 6;
  const int m = wv >> 1, nq = wv & 1;
  const int hi = lane >> 5, lo = lane & 31;

  // packed B fragment bases: frag(ep) at pBp + ep*512
  const f16* pBp[2][2];
#pragma unroll
  for (int n = 0; n < 2; ++n) {
    const int nb = nh * 4 + nq * 2 + n;
    pBp[n][0] = lwp0 + ((size_t)nb * 16384 + lane) * 8;
    pBp[n][1] = lwp1 + ((size_t)nb * 16384 + lane) * 8;
  }
  const int aoff = 4 * (m * 32 + lo) + 8 * hi;

  const int sr = tid >> 5, sc = tid & 31;          // stage row 0..7, chunk 0..31
  const int slimb = sr >> 2, ske = sr & 3;
  const bool has2 = sc < 2;
  const f16* ysrc = (slimb ? yh1 : yh0);

  f32x16 accH[2], accL[2];
#pragma unroll
  for (int n = 0; n < 2; ++n)
#pragma unroll
    for (int r = 0; r < 16; ++r) { accH[n][r] = 0.f; accL[n][r] = 0.f; }

  // ---- B prefetch prologue: slots 0..3 <- ep 0..3 ----
  f16x8 bf[4][2][2];   // [slot(=ke)][n][limb]
#pragma unroll
  for (int d = 0; d < 4; ++d)
#pragma unroll
    for (int n = 0; n < 2; ++n) {
      bf[d][n][0] = *(const f16x8*)(pBp[n][0] + (size_t)d * 512);
      bf[d][n][1] = *(const f16x8*)(pBp[n][1] + (size_t)d * 512);
    }

  { // prologue: stage ss=0 into buf0
    const f16* src = ysrc + ((size_t)(b * EE + ske) * PT + p0) + sc * 8;
    const float4 sA = *(const float4*)src;
    float4 sB{};
    if (has2) sB = *(const float4*)(src + 256);
    f16* dst = &ysh[0][slimb][ske][sc * 8];
    *(float4*)dst = sA;
    if (has2) *(float4*)(dst + 256) = sB;
  }
  __syncthreads();

  for (int ss = 0; ss < 64; ++ss) {
    const int cur = ss & 1;
    const int ssn = (ss < 63) ? ss + 1 : 63;
    // issue next-tile staging loads early (landed after the ke loop)
    const f16* src = ysrc + ((size_t)(b * EE + ssn * 4 + ske) * PT + p0) + sc * 8;
    const float4 sA = *(const float4*)src;
    float4 sB{};
    if (has2) sB = *(const float4*)(src + 256);

    // A-fragments for ke=0
    const f16* ab0 = &ysh[cur][0][0][0] + aoff;
    f16x8 a0 = ldsfrag(ab0);
    f16x8 a1 = ldsfrag(ab0 + 4 * 272);

#pragma unroll
    for (int ke = 0; ke < 4; ++ke) {
      // prefetch next ke's A-fragments from LDS
      f16x8 a0n, a1n;
      if (ke < 3) {
        const f16* abn = &ysh[cur][0][ke + 1][0] + aoff;
        a0n = ldsfrag(abn);
        a1n = ldsfrag(abn + 4 * 272);
      }
      // consume slot ke
#pragma unroll
      for (int n = 0; n < 2; ++n) {
        accH[n] = MFMA16(a0, bf[ke][n][0], accH[n]);
        accL[n] = MFMA16(a0, bf[ke][n][1], accL[n]);
        accL[n] = MFMA16(a1, bf[ke][n][0], accL[n]);
      }
      // reload slot ke from ep+4 (4-deep in-flight window)
      {
        const int epn = ss * 4 + ke + 4;
        const size_t off = (size_t)((epn < 256) ? epn : 255) * 512;
#pragma unroll
        for (int n = 0; n < 2; ++n) {
          bf[ke][n][0] = *(const f16x8*)(pBp[n][0] + off);
          bf[ke][n][1] = *(const f16x8*)(pBp[n][1] + off);
        }
      }
      if (ke < 3) { a0 = a0n; a1 = a1n; }
    }

    { // write staged rows into the other buffer
      f16* dst = &ysh[cur ^ 1][slimb][ske][sc * 8];
      *(float4*)dst = sA;
      if (has2) *(float4*)(dst + 256) = sB;
    }
    __syncthreads();
  }

  // epilogue: e = accH + accL/2048 + lin_b; split to limbs; store
#pragma unroll
  for (int n = 0; n < 2; ++n) {
    const int eo = nh * 128 + (nq * 2 + n) * 32 + lo;
    const float lb = lin_b[eo];
#pragma unroll
    for (int r = 0; r < 16; ++r) {
      const int wloc = m * 32 + (r & 3) + 8 * (r >> 2) + 4 * hi;
      const float v = accH[n][r] + accL[n][r] * INV2048 + lb;
      const h2 s = split2(v);
      const size_t o = (size_t)(mt * 64 + wloc) * EE + eo;
      eh0[o] = s.hi; eh1[o] = s.lo;
    }
  }
}

// ================= k3: distance MFMA + argmax(-argmin) + gather =================
__global__ __launch_bounds__(512, 1)
void k3_dist(const f16* __restrict__ eh0, const f16* __restrict__ eh1,
             const f16* __restrict__ cbp0, const f16* __restrict__ cbp1,
             const float* __restrict__ hn, const float* __restrict__ cbk,
             float* __restrict__ out)
{
  __shared__ __align__(16) f16 esh[2][64][136];   // [limb][w][k-half]
  __shared__ float scs[4][64];
  __shared__ int   scj[4][64];
  __shared__ int   bestj[64];
  const int tid = threadIdx.x;
  const int w0 = blockIdx.x * 64;
  const int lane = tid & 63, wv = tid >> 6;
  const int m = wv & 1, jg = wv >> 1;
  const int hi = lane >> 5, lo = lane & 31;

  // packed codebook fragment bases: frag(ks) at pBp + ks*512
  const f16* pBp[4][2];
  float hnv[4];
#pragma unroll
  for (int q = 0; q < 4; ++q) {
    const int jb = jg * 4 + q;
    pBp[q][0] = cbp0 + ((size_t)jb * 1024 + lane) * 8;
    pBp[q][1] = cbp1 + ((size_t)jb * 1024 + lane) * 8;
    hnv[q] = hn[jb * 32 + lo];
  }
  f32x16 accH[4], accL[4];
#pragma unroll
  for (int q = 0; q < 4; ++q)
#pragma unroll
    for (int r = 0; r < 16; ++r) { accH[q][r] = 0.f; accL[q][r] = 0.f; }

  const int ar = m * 32 + lo;
  f16x8 BA[4][2], BB[4][2];
#pragma unroll
  for (int q = 0; q < 4; ++q) {
    BA[q][0] = *(const f16x8*)(pBp[q][0]);
    BA[q][1] = *(const f16x8*)(pBp[q][1]);
  }

  for (int kh = 0; kh < 2; ++kh) {
    if (kh) __syncthreads();   // prior half's reads done before overwrite
    { // stage e-limb half: rows 64, 128 k each
      const int r = tid >> 3, c8 = tid & 7;
      const f16* s0 = eh0 + (size_t)(w0 + r) * EE + kh * 128;
      const f16* s1 = eh1 + (size_t)(w0 + r) * EE + kh * 128;
#pragma unroll
      for (int i = 0; i < 2; ++i) {
        const int c = (c8 * 2 + i) * 8;
        *(float4*)&esh[0][r][c] = *(const float4*)(s0 + c);
        *(float4*)&esh[1][r][c] = *(const float4*)(s1 + c);
      }
    }
    __syncthreads();
#pragma unroll
    for (int ksl = 0; ksl < 8; ++ksl) {
      const int ks = kh * 8 + ksl;
      const int ksn = (ks < 15) ? ks + 1 : 15;
      const f16x8 a0 = *(const f16x8*)(&esh[0][ar][0] + ksl * 16 + 8 * hi);
      const f16x8 a1 = *(const f16x8*)(&esh[1][ar][0] + ksl * 16 + 8 * hi);
      if ((ks & 1) == 0) {
#pragma unroll
        for (int q = 0; q < 4; ++q) {
          BB[q][0] = *(const f16x8*)(pBp[q][0] + (size_t)ksn * 512);
          BB[q][1] = *(const f16x8*)(pBp[q][1] + (size_t)ksn * 512);
        }
#pragma unroll
        for (int q = 0; q < 4; ++q) {
          accH[q] = MFMA16(a0, BA[q][0], accH[q]);
          accL[q] = MFMA16(a0, BA[q][1], accL[q]);
          accL[q] = MFMA16(a1, BA[q][0], accL[q]);
        }
      } else {
#pragma unroll
        for (int q = 0; q < 4; ++q) {
          BA[q][0] = *(const f16x8*)(pBp[q][0] + (size_t)ksn * 512);
          BA[q][1] = *(const f16x8*)(pBp[q][1] + (size_t)ksn * 512);
        }
#pragma unroll
        for (int q = 0; q < 4; ++q) {
          accH[q] = MFMA16(a0, BB[q][0], accH[q]);
          accL[q] = MFMA16(a0, BB[q][1], accL[q]);
          accL[q] = MFMA16(a1, BB[q][0], accL[q]);
        }
      }
    }
  }

  // per-w argmax over j (min-index tie-break)
#pragma unroll
  for (int r = 0; r < 16; ++r) {
    float bs = accH[0][r] + accL[0][r] * INV2048 - hnv[0];
    int   bj = (jg * 4 + 0) * 32 + lo;
#pragma unroll
    for (int q = 1; q < 4; ++q) {
      const float s = accH[q][r] + accL[q][r] * INV2048 - hnv[q];
      const int   j = (jg * 4 + q) * 32 + lo;
      if (s > bs) { bs = s; bj = j; }   // ascending j: strict > keeps lowest
    }
#pragma unroll
    for (int d = 1; d < 32; d <<= 1) {
      const float os = __shfl_xor(bs, d, 64);
      const int   oj = __shfl_xor(bj, d, 64);
      if (os > bs || (os == bs && oj < bj)) { bs = os; bj = oj; }
    }
    if (lo == 0) {
      const int wloc = m * 32 + (r & 3) + 8 * (r >> 2) + 4 * hi;
      scs[jg][wloc] = bs; scj[jg][wloc] = bj;
    }
  }
  __syncthreads();
  if (tid < 64) {
    float bs = scs[0][tid]; int bj = scj[0][tid];
#pragma unroll
    for (int g = 1; g < 4; ++g) {
      const float s = scs[g][tid]; const int j = scj[g][tid];
      if (s > bs || (s == bs && j < bj)) { bs = s; bj = j; }
    }
    bestj[tid] = bj;
  }
  __syncthreads();
  { // gather codebook rows to output
    const int rr = tid >> 6;          // 0..7
    const int c4 = (tid & 63) * 4;
#pragma unroll
    for (int pass = 0; pass < 8; ++pass) {
      const int r = pass * 8 + rr;
      const int jb = bestj[r];
      const float4 v = *(const float4*)(cbk + (size_t)jb * EE + c4);
      *(float4*)(out + (size_t)(w0 + r) * EE + c4) = v;
    }
  }
}

// ================= fallback: R1 fused VALU kernel (known-good) =================
#define V 8
#define LAGS 4
#define WIN 64
#define STEP 16
#define CONV_OUT 16
#define WPB 16
#define TPB 256
#define NWORD 19
#define YSTRIDE 80
#define XSPAN 304
#define FOFF_YS   0
#define FOFF_XS   10240
#define FOFF_ES   10240
#define FOFF_SC   0
#define FOFF_SI   4096
#define FOFF_PS   8192
#define FOFF_PI   8448
#define FOFF_IW   8704
#define SMEM_FLOATS 14336

__device__ __forceinline__ float f4get(const float4& v, int i) {
  return i == 0 ? v.x : (i == 1 ? v.y : (i == 2 ? v.z : v.w));
}

__device__ __forceinline__ float conv_one(const float* xs, int p, const float4* cw, float cb0) {
  float a = cb0;
#pragma unroll
  for (int v = 0; v < V; ++v) {
    const float4 xv = *(const float4*)(xs + v * XSPAN + 4 * p);
    a = fmaf(xv.x, cw[v].x, a);
    a = fmaf(xv.y, cw[v].y, a);
    a = fmaf(xv.z, cw[v].z, a);
    a = fmaf(xv.w, cw[v].w, a);
  }
  return fmaxf(a, 0.0f);
}

__global__ __launch_bounds__(TPB, 2)
void tok_fused(const float* __restrict__ x, const float* __restrict__ conv_w,
               const float* __restrict__ conv_b, const float* __restrict__ lin_w,
               const float* __restrict__ lin_b, const float* __restrict__ cbk,
               float* __restrict__ out)
{
  __shared__ float smem[SMEM_FLOATS];
  float* ys = smem + FOFF_YS;
  float* xs = smem + FOFF_XS;
  float* es = smem + FOFF_ES;
  float* sc = smem + FOFF_SC;
  int*   si = (int*)(smem + FOFF_SI);
  float* ps = smem + FOFF_PS;
  int*   pi = (int*)(smem + FOFF_PI);
  int*   iw = (int*)(smem + FOFF_IW);
  const int tid = threadIdx.x;
  const int b   = blockIdx.x >> 5;
  const int t0  = (blockIdx.x & 31) * WPB;
  const float* xb = x + (size_t)b * V * SSN + (size_t)t0 * STEP;
#pragma unroll
  for (int v = 0; v < V; ++v)
    for (int j = tid; j < XSPAN; j += TPB)
      xs[v * XSPAN + j] = xb[(size_t)v * SSN + j];
  double accd[WPB];
#pragma unroll
  for (int w = 0; w < WPB; ++w) accd[w] = 0.0;
  for (int half = 0; half < 2; ++half) {
    __syncthreads();
    {
      const int ep  = half * 128 + (tid >> 1);
      const int row = ep & 127;
      float4 cw[V];
      const float4* cwp = (const float4*)(conv_w + (size_t)ep * (V * LAGS));
#pragma unroll
      for (int v = 0; v < V; ++v) cw[v] = cwp[v];
      const float cb0 = conv_b[ep];
      const int c0 = (tid & 1) ? 10 : 0;
      const int c1 = (tid & 1) ? NWORD : 10;
      for (int c = c0; c < c1; ++c) {
        const int p = 4 * c;
        float r0 = conv_one(xs, p + 0, cw, cb0);
        float r1 = conv_one(xs, p + 1, cw, cb0);
        float r2 = conv_one(xs, p + 2, cw, cb0);
        float r3 = conv_one(xs, p + 3, cw, cb0);
        *(float4*)(ys + row * YSTRIDE + 4 * c) = make_float4(r0, r1, r2, r3);
      }
    }
    __syncthreads();
    const float* lwbase = lin_w + (size_t)tid * (EE * CONV_OUT) + half * (128 * CONV_OUT);
    float4 nA, nB, nC, nD;
    {
      const float4* p4 = (const float4*)(lwbase);
      nA = p4[0]; nB = p4[1]; nC = p4[2]; nD = p4[3];
    }
    for (int er = 0; er < 128; ++er) {
      const float4 lA = nA, lB = nB, lC = nC, lD = nD;
      const int ern = (er + 1) & 127;
      {
        const float4* p4 = (const float4*)(lwbase + ern * CONV_OUT);
        nA = p4[0]; nB = p4[1]; nC = p4[2]; nD = p4[3];
      }
      float4 yr[NWORD];
      const float4* yp = (const float4*)(ys + er * YSTRIDE);
#pragma unroll
      for (int q = 0; q < NWORD; ++q) yr[q] = yp[q];
      float it[WPB];
#pragma unroll
      for (int w = 0; w < WPB; ++w) it[w] = 0.0f;
#pragma unroll
      for (int o = 0; o < CONV_OUT; ++o) {
        const float lw_o = f4get(o < 4 ? lA : (o < 8 ? lB : (o < 12 ? lC : lD)), o & 3);
#pragma unroll
        for (int w = 0; w < WPB; ++w) {
          const int p = 4 * w + o;
          it[w] = fmaf(lw_o, f4get(yr[p >> 2], p & 3), it[w]);
        }
      }
#pragma unroll
      for (int w = 0; w < WPB; ++w) accd[w] += (double)it[w];
    }
  }
#pragma unroll
  for (int w = 0; w < WPB; ++w)
    es[w * EE + tid] = (float)accd[w] + lin_b[tid];
  __syncthreads();
  float s_best[WPB];
  int   i_best[WPB];
#pragma unroll
  for (int jj = 0; jj < 2; ++jj) {
    const int j = tid + jj * 256;
    const float4* cbp = (const float4*)(cbk + (size_t)j * EE);
    double sdd[WPB];
    float  sd32[WPB];
#pragma unroll
    for (int w = 0; w < WPB; ++w) { sdd[w] = 0.0; sd32[w] = 0.f; }
    double ndd = 0.0;
    float  nd32 = 0.f;
    float4 c4n = cbp[0];
    for (int i16 = 0; i16 < 4; ++i16) {
      for (int i4i = 0; i4i < 16; ++i4i) {
        const int i4 = i16 * 16 + i4i;
        const float4 c4 = c4n;
        c4n = cbp[(i4 + 1 <= 63) ? (i4 + 1) : 63];
        nd32 = fmaf(c4.x, c4.x, nd32);
        nd32 = fmaf(c4.y, c4.y, nd32);
        nd32 = fmaf(c4.z, c4.z, nd32);
        nd32 = fmaf(c4.w, c4.w, nd32);
#pragma unroll
        for (int w = 0; w < WPB; ++w) {
          const float4 e4 = *(const float4*)(es + w * EE + i4 * 4);
          sd32[w] = fmaf(c4.x, e4.x, sd32[w]);
          sd32[w] = fmaf(c4.y, e4.y, sd32[w]);
          sd32[w] = fmaf(c4.z, e4.z, sd32[w]);
          sd32[w] = fmaf(c4.w, e4.w, sd32[w]);
        }
      }
#pragma unroll
      for (int w = 0; w < WPB; ++w) { sdd[w] += (double)sd32[w]; sd32[w] = 0.f; }
      ndd += (double)nd32; nd32 = 0.f;
    }
#pragma unroll
    for (int w = 0; w < WPB; ++w) {
      const float s = (float)(sdd[w] - 0.5 * ndd);
      if (jj == 0) { s_best[w] = s; i_best[w] = j; }
      else if (s > s_best[w]) { s_best[w] = s; i_best[w] = j; }
    }
  }
#pragma unroll
  for (int w = 0; w < WPB; ++w) {
    sc[w * EE + tid] = s_best[w];
    si[w * EE + tid] = i_best[w];
  }
  __syncthreads();
  {
    const int w = tid >> 4, seg = tid & 15;
    float mm = -INFINITY; int mi = 0x7fffffff;
    for (int t = seg * 16; t < seg * 16 + 16; ++t) {
      const float s = sc[w * EE + t];
      const int   jx = si[w * EE + t];
      if (s > mm || (s == mm && jx < mi)) { mm = s; mi = jx; }
    }
    ps[w * 16 + seg] = mm; pi[w * 16 + seg] = mi;
  }
  __syncthreads();
  if (tid < WPB) {
    const int w = tid;
    float mm = -INFINITY; int mi = 0x7fffffff;
    for (int t = 0; t < 16; ++t) {
      const float s = ps[w * 16 + t];
      const int   jx = pi[w * 16 + t];
      if (s > mm || (s == mm && jx < mi)) { mm = s; mi = jx; }
    }
    iw[w] = mi;
  }
  __syncthreads();
  const size_t outb = ((size_t)b * TTOT + t0) * EE;
#pragma unroll
  for (int w = 0; w < WPB; ++w)
    out[outb + (size_t)w * EE + tid] = cbk[(size_t)iw[w] * EE + tid];
}

// ================= launch =================
extern "C" void kernel_launch(void* const* d_in, const int* in_sizes, int n_in,
                              void* d_out, int out_size, void* d_ws, size_t ws_size,
                              hipStream_t stream) {
  const float* x      = (const float*)d_in[0];
  const float* conv_w = (const float*)d_in[1];
  const float* conv_b = (const float*)d_in[2];
  const float* lin_w  = (const float*)d_in[3];
  const float* lin_b  = (const float*)d_in[4];
  const float* cbk    = (const float*)d_in[5];
  float* out = (float*)d_out;

  if (ws_size < WS_NEED) {
    tok_fused<<<dim3(32 * 32), dim3(TPB), 0, stream>>>(x, conv_w, conv_b, lin_w, lin_b, cbk, out);
    return;
  }
  char* ws = (char*)d_ws;
  f16*   y0  = (f16*)(ws + OFF_Y0);
  f16*   y1  = (f16*)(ws + OFF_Y1);
  f16*   lwp0 = (f16*)(ws + OFF_LW0);
  f16*   lwp1 = (f16*)(ws + OFF_LW1);
  f16*   cbp0 = (f16*)(ws + OFF_CB0);
  f16*   cbp1 = (f16*)(ws + OFF_CB1);
  float* hn  = (float*)(ws + OFF_HN);
  f16*   e0  = (f16*)(ws + OFF_E0);
  f16*   e1  = (f16*)(ws + OFF_E1);

  k0_split<<<272, 256, 0, stream>>>(lin_w, cbk, lwp0, lwp1, cbp0, cbp1, hn);
  k1_conv <<<576, 256, 0, stream>>>(x, conv_w, conv_b, y0, y1);
  k2_linear<<<512, 256, 0, stream>>>(y0, y1, lwp0, lwp1, lin_b, e0, e1);
  k3_dist <<<256, 512, 0, stream>>>(e0, e1, cbp0, cbp1, hn, cbk, out);
}

// Round 7
// 185.268 us; speedup vs baseline: 1.9051x; 1.0559x over previous
//
#include <hip/hip_runtime.h>

typedef _Float16 f16;
typedef _Float16 f16x4 __attribute__((ext_vector_type(4)));
typedef _Float16 f16x8 __attribute__((ext_vector_type(8)));
typedef float    f32x16 __attribute__((ext_vector_type(16)));

#define NB 32
#define TTOT 512
#define SSN 8256
#define PT 2064
#define EE 256
#define KCB 512

// ---------------- ws layout (bytes) ----------------
#define YB   ((size_t)NB*EE*PT*2)
#define LWB  ((size_t)EE*4096*2)
#define CBB  ((size_t)KCB*EE*2)
#define EBB  ((size_t)16384*EE*2)
#define OFF_Y0  ((size_t)0)
#define OFF_Y1  (YB)
#define OFF_LW0 (2*YB)
#define OFF_LW1 (2*YB + LWB)
#define OFF_CB0 (2*YB + 2*LWB)
#define OFF_CB1 (2*YB + 2*LWB + CBB)
#define OFF_HN  (2*YB + 2*LWB + 2*CBB)
#define OFF_E0  (OFF_HN + 4096)
#define OFF_E1  (OFF_E0 + EBB)
#define WS_NEED (OFF_E1 + EBB)

#define INV2048 4.8828125e-4f

struct h2 { f16 hi, lo; };
__device__ __forceinline__ h2 split2(float v) {
  h2 r;
  r.hi = (f16)v;
  r.lo = (f16)((v - (float)r.hi) * 2048.0f);
  return r;
}

__device__ __forceinline__ f16x8 ldsfrag(const f16* p) {
  union { f16x8 v8; f16x4 v4[2]; } u;
  u.v4[0] = *(const f16x4*)p;
  u.v4[1] = *(const f16x4*)(p + 4);
  return u.v8;
}

#define MFMA16(a,b,c) __builtin_amdgcn_mfma_f32_32x32x16_f16(a, b, c, 0, 0, 0)

// ================= k01: fused repack (k0) + conv (k1) =================
// blocks [0,272): k0 repack lin_w/codebook into MFMA-fragment order + half-norms
// blocks [272,848): k1 conv -> y limbs
__global__ __launch_bounds__(256, 2)
void k01(const float* __restrict__ lin_w, const float* __restrict__ cbk,
         f16* __restrict__ lwp0, f16* __restrict__ lwp1,
         f16* __restrict__ cbp0, f16* __restrict__ cbp1, float* __restrict__ hn,
         const float* __restrict__ x, const float* __restrict__ cw,
         const float* __restrict__ cb, f16* __restrict__ y0, f16* __restrict__ y1)
{
  __shared__ float part[4][32];
  const int tid = threadIdx.x;
  const int bix = blockIdx.x;
  if (bix < 272) {
    const int bid = bix;
    if (bid < 256) {
      const int eo = bid, nb = eo >> 5, lo = eo & 31;
      const int ep = tid;
      const float* src = lin_w + (size_t)eo * 4096 + ep * 16;
      float f[16];
      *(float4*)(f + 0)  = ((const float4*)src)[0];
      *(float4*)(f + 4)  = ((const float4*)src)[1];
      *(float4*)(f + 8)  = ((const float4*)src)[2];
      *(float4*)(f + 12) = ((const float4*)src)[3];
      union { f16x8 v; f16 e[8]; } a0, a1, b0, b1;
#pragma unroll
      for (int i = 0; i < 8; ++i) {
        { h2 s = split2(f[i]);     a0.e[i] = s.hi; a1.e[i] = s.lo; }
        { h2 s = split2(f[i + 8]); b0.e[i] = s.hi; b1.e[i] = s.lo; }
      }
      const size_t base = ((size_t)nb * 16384 + (size_t)ep * 64 + lo) * 8;
      *(f16x8*)(lwp0 + base)       = a0.v;   // lane hi=0 slot
      *(f16x8*)(lwp0 + base + 256) = b0.v;   // lane hi=1 slot
      *(f16x8*)(lwp1 + base)       = a1.v;
      *(f16x8*)(lwp1 + base + 256) = b1.v;
    } else {
      const int jb = bid - 256;              // 0..15
      const int lane = tid & 63, ksg = tid >> 6;
      const int hi = lane >> 5, lo = lane & 31;
      const int j = jb * 32 + lo;
      float s = 0.f;
#pragma unroll
      for (int kq = 0; kq < 4; ++kq) {
        const int ks = ksg * 4 + kq;
        const float* src = cbk + (size_t)j * 256 + ks * 16 + 8 * hi;
        float f[8];
        *(float4*)(f + 0) = ((const float4*)src)[0];
        *(float4*)(f + 4) = ((const float4*)src)[1];
        union { f16x8 v; f16 e[8]; } h0, h1;
#pragma unroll
        for (int i = 0; i < 8; ++i) {
          s = fmaf(f[i], f[i], s);
          h2 t = split2(f[i]); h0.e[i] = t.hi; h1.e[i] = t.lo;
        }
        const size_t base = ((size_t)jb * 1024 + (size_t)ks * 64 + lane) * 8;
        *(f16x8*)(cbp0 + base) = h0.v;
        *(f16x8*)(cbp1 + base) = h1.v;
      }
      s += __shfl_xor(s, 32, 64);            // fold hi=0/1
      if (lane < 32) part[ksg][lane] = s;
      __syncthreads();
      if (tid < 32)
        hn[jb * 32 + tid] = 0.5f * (part[0][tid] + part[1][tid] + part[2][tid] + part[3][tid]);
    }
  } else {
    const int bid = bix - 272;               // 0..575
    const int b = bid / 18, rem = bid % 18;
    const int eq = rem / 9, ptile = rem % 9;
    const int p = ptile * 256 + tid;
    const bool valid = p < PT;
    const int pc = valid ? p : (PT - 1);
    float4 xv[8];
#pragma unroll
    for (int v = 0; v < 8; ++v)
      xv[v] = *(const float4*)(x + ((size_t)b * 8 + v) * SSN + 4 * pc);
    const int e0 = eq * 128;
    float4 wc[8], wn[8];
#pragma unroll
    for (int v = 0; v < 8; ++v) wc[v] = *(const float4*)(cw + (size_t)e0 * 32 + v * 4);
    for (int ep = e0; ep < e0 + 128; ++ep) {
      const int epn = (ep + 1 < e0 + 128) ? ep + 1 : ep;
#pragma unroll
      for (int v = 0; v < 8; ++v) wn[v] = *(const float4*)(cw + (size_t)epn * 32 + v * 4);
      float a = cb[ep];
#pragma unroll
      for (int v = 0; v < 8; ++v) {
        a = fmaf(xv[v].x, wc[v].x, a);
        a = fmaf(xv[v].y, wc[v].y, a);
        a = fmaf(xv[v].z, wc[v].z, a);
        a = fmaf(xv[v].w, wc[v].w, a);
      }
      a = fmaxf(a, 0.f);
      if (valid) {
        const h2 s = split2(a);
        const size_t o = ((size_t)b * EE + ep) * PT + p;
        y0[o] = s.hi; y1[o] = s.lo;
      }
#pragma unroll
      for (int v = 0; v < 8; ++v) wc[v] = wn[v];
    }
  }
}

// ================= k2: linear GEMM via MFMA -> e limbs =================
// 256 blocks = 128 M-tiles(128w) x 2 N-halves(128eo); 512 threads = 8 waves (4m x 2nq).
// B staged in LDS once per block (shared by m-waves), double-buffered; y likewise.
__global__ __launch_bounds__(512, 1)
void k2_linear(const f16* __restrict__ yh0, const f16* __restrict__ yh1,
               const f16* __restrict__ lwp0, const f16* __restrict__ lwp1,
               const float* __restrict__ lin_b,
               f16* __restrict__ eh0, f16* __restrict__ eh1)
{
  __shared__ __align__(16) f16 ysh[2][2][4][528];       // [buf][limb][ke][pos] 16.9KB
  __shared__ __align__(16) f16 bsh[2][4][4][2][512];    // [buf][ke][nb][limb][frag] 64KB
  const int tid = threadIdx.x;
  // XCD-aware swizzle over 256 blocks (bijective: 256 % 8 == 0)
  const int sw = (blockIdx.x & 7) * 32 + (blockIdx.x >> 3);
  const int nh = sw >> 7, mt = sw & 127;
  const int b = mt >> 2;
  const int p0 = (mt & 3) * 512;
  const int lane = tid & 63, wv = tid >> 6;
  const int m = wv >> 1, nq = wv & 1;
  const int hi = lane >> 5, lo = lane & 31;
  const int aoff = 4 * (m * 32 + lo) + 8 * hi;

  // B staging: wave wv stages ke=wv>>1, nb in {(wv&1)*2, +1}, both limbs (4 x 1KB frags)
  const int bke = wv >> 1;
  const int bnb0 = (wv & 1) * 2;
  const f16* bs[2][2];
#pragma unroll
  for (int j = 0; j < 2; ++j) {
    bs[j][0] = lwp0 + ((size_t)(nh * 4 + bnb0 + j) * 256) * 512 + lane * 8;
    bs[j][1] = lwp1 + ((size_t)(nh * 4 + bnb0 + j) * 256) * 512 + lane * 8;
  }
  // y staging: wave wv stages row (limb=wv>>2, ke=wv&3): 528 f16, lane-contiguous
  const int ylimb = wv >> 2, yke = wv & 3;
  const f16* ysrcp = ylimb ? yh1 : yh0;
  const size_t ybase0 = ((size_t)b * EE + yke) * PT + p0 + lane * 8;

  f32x16 accH[2], accL[2];
#pragma unroll
  for (int n = 0; n < 2; ++n)
#pragma unroll
    for (int r = 0; r < 16; ++r) { accH[n][r] = 0.f; accL[n][r] = 0.f; }

  { // prologue: stage ss=0 into buf0
    const size_t epo = (size_t)bke * 512;
    float4 br[4];
#pragma unroll
    for (int i = 0; i < 4; ++i) br[i] = *(const float4*)(bs[i >> 1][i & 1] + epo);
    const float4 ya = *(const float4*)(ysrcp + ybase0);
    float4 yb{};
    if (lane < 2) yb = *(const float4*)(ysrcp + ybase0 + 512);
#pragma unroll
    for (int i = 0; i < 4; ++i)
      *(float4*)&bsh[0][bke][bnb0 + (i >> 1)][i & 1][lane * 8] = br[i];
    f16* yd = &ysh[0][ylimb][yke][lane * 8];
    *(float4*)yd = ya;
    if (lane < 2) *(float4*)(yd + 512) = yb;
  }
  __syncthreads();

  for (int ss = 0; ss < 64; ++ss) {
    const int cur = ss & 1;
    const int ssn = (ss < 63) ? ss + 1 : 63;
    // issue staging loads for ss+1 (land after MFMA block)
    const size_t epo = (size_t)(ssn * 4 + bke) * 512;
    float4 br[4];
#pragma unroll
    for (int i = 0; i < 4; ++i) br[i] = *(const float4*)(bs[i >> 1][i & 1] + epo);
    const size_t yb0 = ybase0 + (size_t)ssn * 4 * PT;
    const float4 ya = *(const float4*)(ysrcp + yb0);
    float4 yb{};
    if (lane < 2) yb = *(const float4*)(ysrcp + yb0 + 512);

    // MFMA on buf[cur]
#pragma unroll
    for (int ke = 0; ke < 4; ++ke) {
      const f16x8 a0 = ldsfrag(&ysh[cur][0][ke][aoff]);
      const f16x8 a1 = ldsfrag(&ysh[cur][1][ke][aoff]);
#pragma unroll
      for (int n = 0; n < 2; ++n) {
        const f16x8 b0 = *(const f16x8*)&bsh[cur][ke][nq * 2 + n][0][lane * 8];
        const f16x8 b1 = *(const f16x8*)&bsh[cur][ke][nq * 2 + n][1][lane * 8];
        accH[n] = MFMA16(a0, b0, accH[n]);
        accL[n] = MFMA16(a0, b1, accL[n]);
        accL[n] = MFMA16(a1, b0, accL[n]);
      }
    }
    { // write staged rows into the other buffer
      const int nxt = cur ^ 1;
#pragma unroll
      for (int i = 0; i < 4; ++i)
        *(float4*)&bsh[nxt][bke][bnb0 + (i >> 1)][i & 1][lane * 8] = br[i];
      f16* yd = &ysh[nxt][ylimb][yke][lane * 8];
      *(float4*)yd = ya;
      if (lane < 2) *(float4*)(yd + 512) = yb;
    }
    __syncthreads();
  }

  // epilogue: e = accH + accL/2048 + lin_b; split to limbs; store
#pragma unroll
  for (int n = 0; n < 2; ++n) {
    const int eo = nh * 128 + (nq * 2 + n) * 32 + lo;
    const float lb = lin_b[eo];
#pragma unroll
    for (int r = 0; r < 16; ++r) {
      const int wloc = m * 32 + (r & 3) + 8 * (r >> 2) + 4 * hi;
      const float v = accH[n][r] + accL[n][r] * INV2048 + lb;
      const h2 s = split2(v);
      const size_t o = (size_t)(mt * 128 + wloc) * EE + eo;
      eh0[o] = s.hi; eh1[o] = s.lo;
    }
  }
}

// ================= k3: distance MFMA + argmax(-argmin) + gather =================
__global__ __launch_bounds__(512, 1)
void k3_dist(const f16* __restrict__ eh0, const f16* __restrict__ eh1,
             const f16* __restrict__ cbp0, const f16* __restrict__ cbp1,
             const float* __restrict__ hn, const float* __restrict__ cbk,
             float* __restrict__ out)
{
  __shared__ __align__(16) f16 esh[2][64][136];   // [limb][w][k-half]
  __shared__ float scs[4][64];
  __shared__ int   scj[4][64];
  __shared__ int   bestj[64];
  const int tid = threadIdx.x;
  const int w0 = blockIdx.x * 64;
  const int lane = tid & 63, wv = tid >> 6;
  const int m = wv & 1, jg = wv >> 1;
  const int hi = lane >> 5, lo = lane & 31;

  // packed codebook fragment bases: frag(ks) at pBp + ks*512
  const f16* pBp[4][2];
  float hnv[4];
#pragma unroll
  for (int q = 0; q < 4; ++q) {
    const int jb = jg * 4 + q;
    pBp[q][0] = cbp0 + ((size_t)jb * 1024 + lane) * 8;
    pBp[q][1] = cbp1 + ((size_t)jb * 1024 + lane) * 8;
    hnv[q] = hn[jb * 32 + lo];
  }
  f32x16 accH[4], accL[4];
#pragma unroll
  for (int q = 0; q < 4; ++q)
#pragma unroll
    for (int r = 0; r < 16; ++r) { accH[q][r] = 0.f; accL[q][r] = 0.f; }

  const int ar = m * 32 + lo;
  f16x8 BA[4][2], BB[4][2];
#pragma unroll
  for (int q = 0; q < 4; ++q) {
    BA[q][0] = *(const f16x8*)(pBp[q][0]);
    BA[q][1] = *(const f16x8*)(pBp[q][1]);
  }

  for (int kh = 0; kh < 2; ++kh) {
    if (kh) __syncthreads();   // prior half's reads done before overwrite
    { // stage e-limb half: rows 64, 128 k each
      const int r = tid >> 3, c8 = tid & 7;
      const f16* s0 = eh0 + (size_t)(w0 + r) * EE + kh * 128;
      const f16* s1 = eh1 + (size_t)(w0 + r) * EE + kh * 128;
#pragma unroll
      for (int i = 0; i < 2; ++i) {
        const int c = (c8 * 2 + i) * 8;
        *(float4*)&esh[0][r][c] = *(const float4*)(s0 + c);
        *(float4*)&esh[1][r][c] = *(const float4*)(s1 + c);
      }
    }
    __syncthreads();
#pragma unroll
    for (int ksl = 0; ksl < 8; ++ksl) {
      const int ks = kh * 8 + ksl;
      const int ksn = (ks < 15) ? ks + 1 : 15;
      const f16x8 a0 = *(const f16x8*)(&esh[0][ar][0] + ksl * 16 + 8 * hi);
      const f16x8 a1 = *(const f16x8*)(&esh[1][ar][0] + ksl * 16 + 8 * hi);
      if ((ks & 1) == 0) {
#pragma unroll
        for (int q = 0; q < 4; ++q) {
          BB[q][0] = *(const f16x8*)(pBp[q][0] + (size_t)ksn * 512);
          BB[q][1] = *(const f16x8*)(pBp[q][1] + (size_t)ksn * 512);
        }
#pragma unroll
        for (int q = 0; q < 4; ++q) {
          accH[q] = MFMA16(a0, BA[q][0], accH[q]);
          accL[q] = MFMA16(a0, BA[q][1], accL[q]);
          accL[q] = MFMA16(a1, BA[q][0], accL[q]);
        }
      } else {
#pragma unroll
        for (int q = 0; q < 4; ++q) {
          BA[q][0] = *(const f16x8*)(pBp[q][0] + (size_t)ksn * 512);
          BA[q][1] = *(const f16x8*)(pBp[q][1] + (size_t)ksn * 512);
        }
#pragma unroll
        for (int q = 0; q < 4; ++q) {
          accH[q] = MFMA16(a0, BB[q][0], accH[q]);
          accL[q] = MFMA16(a0, BB[q][1], accL[q]);
          accL[q] = MFMA16(a1, BB[q][0], accL[q]);
        }
      }
    }
  }

  // per-w argmax over j (min-index tie-break)
#pragma unroll
  for (int r = 0; r < 16; ++r) {
    float bs = accH[0][r] + accL[0][r] * INV2048 - hnv[0];
    int   bj = (jg * 4 + 0) * 32 + lo;
#pragma unroll
    for (int q = 1; q < 4; ++q) {
      const float s = accH[q][r] + accL[q][r] * INV2048 - hnv[q];
      const int   j = (jg * 4 + q) * 32 + lo;
      if (s > bs) { bs = s; bj = j; }   // ascending j: strict > keeps lowest
    }
#pragma unroll
    for (int d = 1; d < 32; d <<= 1) {
      const float os = __shfl_xor(bs, d, 64);
      const int   oj = __shfl_xor(bj, d, 64);
      if (os > bs || (os == bs && oj < bj)) { bs = os; bj = oj; }
    }
    if (lo == 0) {
      const int wloc = m * 32 + (r & 3) + 8 * (r >> 2) + 4 * hi;
      scs[jg][wloc] = bs; scj[jg][wloc] = bj;
    }
  }
  __syncthreads();
  if (tid < 64) {
    float bs = scs[0][tid]; int bj = scj[0][tid];
#pragma unroll
    for (int g = 1; g < 4; ++g) {
      const float s = scs[g][tid]; const int j = scj[g][tid];
      if (s > bs || (s == bs && j < bj)) { bs = s; bj = j; }
    }
    bestj[tid] = bj;
  }
  __syncthreads();
  { // gather codebook rows to output
    const int rr = tid >> 6;          // 0..7
    const int c4 = (tid & 63) * 4;
#pragma unroll
    for (int pass = 0; pass < 8; ++pass) {
      const int r = pass * 8 + rr;
      const int jb = bestj[r];
      const float4 v = *(const float4*)(cbk + (size_t)jb * EE + c4);
      *(float4*)(out + (size_t)(w0 + r) * EE + c4) = v;
    }
  }
}

// ================= fallback: R1 fused VALU kernel (known-good) =================
#define V 8
#define LAGS 4
#define WIN 64
#define STEP 16
#define CONV_OUT 16
#define WPB 16
#define TPB 256
#define NWORD 19
#define YSTRIDE 80
#define XSPAN 304
#define FOFF_YS   0
#define FOFF_XS   10240
#define FOFF_ES   10240
#define FOFF_SC   0
#define FOFF_SI   4096
#define FOFF_PS   8192
#define FOFF_PI   8448
#define FOFF_IW   8704
#define SMEM_FLOATS 14336

__device__ __forceinline__ float f4get(const float4& v, int i) {
  return i == 0 ? v.x : (i == 1 ? v.y : (i == 2 ? v.z : v.w));
}

__device__ __forceinline__ float conv_one(const float* xs, int p, const float4* cw, float cb0) {
  float a = cb0;
#pragma unroll
  for (int v = 0; v < V; ++v) {
    const float4 xv = *(const float4*)(xs + v * XSPAN + 4 * p);
    a = fmaf(xv.x, cw[v].x, a);
    a = fmaf(xv.y, cw[v].y, a);
    a = fmaf(xv.z, cw[v].z, a);
    a = fmaf(xv.w, cw[v].w, a);
  }
  return fmaxf(a, 0.0f);
}

__global__ __launch_bounds__(TPB, 2)
void tok_fused(const float* __restrict__ x, const float* __restrict__ conv_w,
               const float* __restrict__ conv_b, const float* __restrict__ lin_w,
               const float* __restrict__ lin_b, const float* __restrict__ cbk,
               float* __restrict__ out)
{
  __shared__ float smem[SMEM_FLOATS];
  float* ys = smem + FOFF_YS;
  float* xs = smem + FOFF_XS;
  float* es = smem + FOFF_ES;
  float* sc = smem + FOFF_SC;
  int*   si = (int*)(smem + FOFF_SI);
  float* ps = smem + FOFF_PS;
  int*   pi = (int*)(smem + FOFF_PI);
  int*   iw = (int*)(smem + FOFF_IW);
  const int tid = threadIdx.x;
  const int b   = blockIdx.x >> 5;
  const int t0  = (blockIdx.x & 31) * WPB;
  const float* xb = x + (size_t)b * V * SSN + (size_t)t0 * STEP;
#pragma unroll
  for (int v = 0; v < V; ++v)
    for (int j = tid; j < XSPAN; j += TPB)
      xs[v * XSPAN + j] = xb[(size_t)v * SSN + j];
  double accd[WPB];
#pragma unroll
  for (int w = 0; w < WPB; ++w) accd[w] = 0.0;
  for (int half = 0; half < 2; ++half) {
    __syncthreads();
    {
      const int ep  = half * 128 + (tid >> 1);
      const int row = ep & 127;
      float4 cw[V];
      const float4* cwp = (const float4*)(conv_w + (size_t)ep * (V * LAGS));
#pragma unroll
      for (int v = 0; v < V; ++v) cw[v] = cwp[v];
      const float cb0 = conv_b[ep];
      const int c0 = (tid & 1) ? 10 : 0;
      const int c1 = (tid & 1) ? NWORD : 10;
      for (int c = c0; c < c1; ++c) {
        const int p = 4 * c;
        float r0 = conv_one(xs, p + 0, cw, cb0);
        float r1 = conv_one(xs, p + 1, cw, cb0);
        float r2 = conv_one(xs, p + 2, cw, cb0);
        float r3 = conv_one(xs, p + 3, cw, cb0);
        *(float4*)(ys + row * YSTRIDE + 4 * c) = make_float4(r0, r1, r2, r3);
      }
    }
    __syncthreads();
    const float* lwbase = lin_w + (size_t)tid * (EE * CONV_OUT) + half * (128 * CONV_OUT);
    float4 nA, nB, nC, nD;
    {
      const float4* p4 = (const float4*)(lwbase);
      nA = p4[0]; nB = p4[1]; nC = p4[2]; nD = p4[3];
    }
    for (int er = 0; er < 128; ++er) {
      const float4 lA = nA, lB = nB, lC = nC, lD = nD;
      const int ern = (er + 1) & 127;
      {
        const float4* p4 = (const float4*)(lwbase + ern * CONV_OUT);
        nA = p4[0]; nB = p4[1]; nC = p4[2]; nD = p4[3];
      }
      float4 yr[NWORD];
      const float4* yp = (const float4*)(ys + er * YSTRIDE);
#pragma unroll
      for (int q = 0; q < NWORD; ++q) yr[q] = yp[q];
      float it[WPB];
#pragma unroll
      for (int w = 0; w < WPB; ++w) it[w] = 0.0f;
#pragma unroll
      for (int o = 0; o < CONV_OUT; ++o) {
        const float lw_o = f4get(o < 4 ? lA : (o < 8 ? lB : (o < 12 ? lC : lD)), o & 3);
#pragma unroll
        for (int w = 0; w < WPB; ++w) {
          const int p = 4 * w + o;
          it[w] = fmaf(lw_o, f4get(yr[p >> 2], p & 3), it[w]);
        }
      }
#pragma unroll
      for (int w = 0; w < WPB; ++w) accd[w] += (double)it[w];
    }
  }
#pragma unroll
  for (int w = 0; w < WPB; ++w)
    es[w * EE + tid] = (float)accd[w] + lin_b[tid];
  __syncthreads();
  float s_best[WPB];
  int   i_best[WPB];
#pragma unroll
  for (int jj = 0; jj < 2; ++jj) {
    const int j = tid + jj * 256;
    const float4* cbp = (const float4*)(cbk + (size_t)j * EE);
    double sdd[WPB];
    float  sd32[WPB];
#pragma unroll
    for (int w = 0; w < WPB; ++w) { sdd[w] = 0.0; sd32[w] = 0.f; }
    double ndd = 0.0;
    float  nd32 = 0.f;
    float4 c4n = cbp[0];
    for (int i16 = 0; i16 < 4; ++i16) {
      for (int i4i = 0; i4i < 16; ++i4i) {
        const int i4 = i16 * 16 + i4i;
        const float4 c4 = c4n;
        c4n = cbp[(i4 + 1 <= 63) ? (i4 + 1) : 63];
        nd32 = fmaf(c4.x, c4.x, nd32);
        nd32 = fmaf(c4.y, c4.y, nd32);
        nd32 = fmaf(c4.z, c4.z, nd32);
        nd32 = fmaf(c4.w, c4.w, nd32);
#pragma unroll
        for (int w = 0; w < WPB; ++w) {
          const float4 e4 = *(const float4*)(es + w * EE + i4 * 4);
          sd32[w] = fmaf(c4.x, e4.x, sd32[w]);
          sd32[w] = fmaf(c4.y, e4.y, sd32[w]);
          sd32[w] = fmaf(c4.z, e4.z, sd32[w]);
          sd32[w] = fmaf(c4.w, e4.w, sd32[w]);
        }
      }
#pragma unroll
      for (int w = 0; w < WPB; ++w) { sdd[w] += (double)sd32[w]; sd32[w] = 0.f; }
      ndd += (double)nd32; nd32 = 0.f;
    }
#pragma unroll
    for (int w = 0; w < WPB; ++w) {
      const float s = (float)(sdd[w] - 0.5 * ndd);
      if (jj == 0) { s_best[w] = s; i_best[w] = j; }
      else if (s > s_best[w]) { s_best[w] = s; i_best[w] = j; }
    }
  }
#pragma unroll
  for (int w = 0; w < WPB; ++w) {
    sc[w * EE + tid] = s_best[w];
    si[w * EE + tid] = i_best[w];
  }
  __syncthreads();
  {
    const int w = tid >> 4, seg = tid & 15;
    float mm = -INFINITY; int mi = 0x7fffffff;
    for (int t = seg * 16; t < seg * 16 + 16; ++t) {
      const float s = sc[w * EE + t];
      const int   jx = si[w * EE + t];
      if (s > mm || (s == mm && jx < mi)) { mm = s; mi = jx; }
    }
    ps[w * 16 + seg] = mm; pi[w * 16 + seg] = mi;
  }
  __syncthreads();
  if (tid < WPB) {
    const int w = tid;
    float mm = -INFINITY; int mi = 0x7fffffff;
    for (int t = 0; t < 16; ++t) {
      const float s = ps[w * 16 + t];
      const int   jx = pi[w * 16 + t];
      if (s > mm || (s == mm && jx < mi)) { mm = s; mi = jx; }
    }
    iw[w] = mi;
  }
  __syncthreads();
  const size_t outb = ((size_t)b * TTOT + t0) * EE;
#pragma unroll
  for (int w = 0; w < WPB; ++w)
    out[outb + (size_t)w * EE + tid] = cbk[(size_t)iw[w] * EE + tid];
}

// ================= launch =================
extern "C" void kernel_launch(void* const* d_in, const int* in_sizes, int n_in,
                              void* d_out, int out_size, void* d_ws, size_t ws_size,
                              hipStream_t stream) {
  const float* x      = (const float*)d_in[0];
  const float* conv_w = (const float*)d_in[1];
  const float* conv_b = (const float*)d_in[2];
  const float* lin_w  = (const float*)d_in[3];
  const float* lin_b  = (const float*)d_in[4];
  const float* cbk    = (const float*)d_in[5];
  float* out = (float*)d_out;

  if (ws_size < WS_NEED) {
    tok_fused<<<dim3(32 * 32), dim3(TPB), 0, stream>>>(x, conv_w, conv_b, lin_w, lin_b, cbk, out);
    return;
  }
  char* ws = (char*)d_ws;
  f16*   y0   = (f16*)(ws + OFF_Y0);
  f16*   y1   = (f16*)(ws + OFF_Y1);
  f16*   lwp0 = (f16*)(ws + OFF_LW0);
  f16*   lwp1 = (f16*)(ws + OFF_LW1);
  f16*   cbp0 = (f16*)(ws + OFF_CB0);
  f16*   cbp1 = (f16*)(ws + OFF_CB1);
  float* hn   = (float*)(ws + OFF_HN);
  f16*   e0   = (f16*)(ws + OFF_E0);
  f16*   e1   = (f16*)(ws + OFF_E1);

  k01<<<848, 256, 0, stream>>>(lin_w, cbk, lwp0, lwp1, cbp0, cbp1, hn,
                               x, conv_w, conv_b, y0, y1);
  k2_linear<<<256, 512, 0, stream>>>(y0, y1, lwp0, lwp1, lin_b, e0, e1);
  k3_dist <<<256, 512, 0, stream>>>(e0, e1, cbp0, cbp1, hn, cbk, out);
}